// Round 1
// baseline (271.824 us; speedup 1.0000x reference)
//
#include <hip/hip_runtime.h>
#include <hip/hip_bf16.h>

// LowRankBilinearFusion on MI355X (gfx950)
// Stage 1: up_bf16 = u @ Wu^T   (1024 x 1024 -> 1024 x 256)   MFMA bf16
// Stage 2: vp_bf16 = v @ Wv^T   (4096 x 2048 -> 4096 x 256)   MFMA bf16
// Stage 3: per (b,m): o = relu( vp[b] @ (up[b,m] (.) Wp)^T + bp )
//          128x256x256 GEMM per (b,m); W' = up (.) Wp fused into LDS staging.

typedef __attribute__((ext_vector_type(8))) short short8;
typedef __attribute__((ext_vector_type(4))) float floatx4;

__device__ __forceinline__ short f2bf(float f) {
    __hip_bfloat16 h = __float2bfloat16(f);
    union { __hip_bfloat16 h; short s; } cv; cv.h = h; return cv.s;
}
__device__ __forceinline__ float bf2f(short s) {
    union { unsigned int u; float f; } cv;
    cv.u = ((unsigned int)(unsigned short)s) << 16; return cv.f;
}

// ---------------------------------------------------------------------------
// Generic projection GEMM: C_bf16[row][c] = sum_d X[row][d] * W[c][d]
// Block tile 64 rows x 64 cols, 256 threads (4 waves, 2x2), K-chunks of 32.
// grid.x = (rows/64) * 4   (4 col-blocks of 64 over 256 cols)
// ---------------------------------------------------------------------------
__global__ __launch_bounds__(256) void proj_kernel(
    const float* __restrict__ X, const float* __restrict__ W,
    short* __restrict__ C, int D)
{
    __shared__ short Xs[64 * 40];   // stride 40 bf16 (80B, 16B-aligned, pads banks)
    __shared__ short Wsh[64 * 40];

    const int tid  = threadIdx.x;
    const int lane = tid & 63;
    const int wave = tid >> 6;
    const int quad = lane >> 4;
    const int l15  = lane & 15;

    const int rblk = blockIdx.x >> 2;
    const int cblk = blockIdx.x & 3;
    const int r0 = rblk * 64;
    const int c0 = cblk * 64;
    const int wr = (wave >> 1) * 32;
    const int wc = (wave & 1) * 32;

    const int sr  = tid >> 2;        // 0..63  staging row
    const int skg = (tid & 3) * 8;   // 0,8,16,24 staging k-group

    floatx4 acc[2][2] = {};

    for (int kc = 0; kc < D; kc += 32) {
        __syncthreads();
        {
            const float* xp = X + (size_t)(r0 + sr) * D + kc + skg;
            float xv[8];
            *(float4*)&xv[0] = *(const float4*)xp;
            *(float4*)&xv[4] = *(const float4*)(xp + 4);
            short8 xs;
#pragma unroll
            for (int i = 0; i < 8; i++) xs[i] = f2bf(xv[i]);
            *(short8*)&Xs[sr * 40 + skg] = xs;

            const float* wp = W + (size_t)(c0 + sr) * D + kc + skg;
            float wv[8];
            *(float4*)&wv[0] = *(const float4*)wp;
            *(float4*)&wv[4] = *(const float4*)(wp + 4);
            short8 ws;
#pragma unroll
            for (int i = 0; i < 8; i++) ws[i] = f2bf(wv[i]);
            *(short8*)&Wsh[sr * 40 + skg] = ws;
        }
        __syncthreads();

        short8 a[2], bfr[2];
#pragma unroll
        for (int t = 0; t < 2; t++)
            a[t] = *(const short8*)&Xs[(wr + t * 16 + l15) * 40 + quad * 8];
#pragma unroll
        for (int t = 0; t < 2; t++)
            bfr[t] = *(const short8*)&Wsh[(wc + t * 16 + l15) * 40 + quad * 8];
#pragma unroll
        for (int tn = 0; tn < 2; tn++)
#pragma unroll
            for (int tf = 0; tf < 2; tf++)
                acc[tn][tf] = __builtin_amdgcn_mfma_f32_16x16x32_bf16(
                    a[tn], bfr[tf], acc[tn][tf], 0, 0, 0);
    }

    // Epilogue: C/D layout col=lane&15, row=quad*4+reg (verified m89/m91)
#pragma unroll
    for (int tn = 0; tn < 2; tn++) {
#pragma unroll
        for (int tf = 0; tf < 2; tf++) {
#pragma unroll
            for (int r = 0; r < 4; r++) {
                int row = r0 + wr + tn * 16 + quad * 4 + r;
                int col = c0 + wc + tf * 16 + l15;
                C[(size_t)row * 256 + col] = f2bf(acc[tn][tf][r]);
            }
        }
    }
}

// ---------------------------------------------------------------------------
// Bilinear fusion kernel. One block = one (b,m) and one 128-wide f-half.
// Block tile: n=128 x f=128, 4 waves in 2x2, each wave 64x64 (4x4 MFMA tiles).
// K-loop: 256 in chunks of 32; W'[f][k] = up[k]*Wp[f][k] built during staging.
// ---------------------------------------------------------------------------
__global__ __launch_bounds__(256) void bilinear_kernel(
    const short* __restrict__ up, const short* __restrict__ vp,
    const float* __restrict__ Wp, const float* __restrict__ bp,
    float* __restrict__ out)
{
    __shared__ short vp_s[128 * 40];
    __shared__ short Ws[128 * 40];
    __shared__ float up_s[256];

    const int tid  = threadIdx.x;
    const int lane = tid & 63;
    const int wave = tid >> 6;
    const int quad = lane >> 4;
    const int l15  = lane & 15;

    const int f_blk = blockIdx.x & 1;
    const int bm    = blockIdx.x >> 1;   // b*32 + m
    const int b     = bm >> 5;
    const int f0    = f_blk * 128;
    const int wn    = (wave >> 1) * 64;
    const int wf    = (wave & 1) * 64;

    up_s[tid] = bf2f(up[(size_t)bm * 256 + tid]);

    const int sn  = tid >> 1;          // 0..127 staging row (n for vp, f for W')
    const int skh = (tid & 1) * 16;    // 0 or 16

    floatx4 acc[4][4] = {};

    for (int kc = 0; kc < 256; kc += 32) {
        __syncthreads();   // also publishes up_s on first iteration
        {   // vp slice: 128 x 32 bf16 copy
            const short* p = vp + (size_t)(b * 128 + sn) * 256 + kc + skh;
            short8 v0 = *(const short8*)p;
            short8 v1 = *(const short8*)(p + 8);
            *(short8*)&vp_s[sn * 40 + skh]     = v0;
            *(short8*)&vp_s[sn * 40 + skh + 8] = v1;
        }
        {   // W' slice: 128 x 32, scaled by up_s[k]
            const float* wp = Wp + (size_t)(f0 + sn) * 256 + kc + skh;
            float wv[16];
            *(float4*)&wv[0]  = *(const float4*)wp;
            *(float4*)&wv[4]  = *(const float4*)(wp + 4);
            *(float4*)&wv[8]  = *(const float4*)(wp + 8);
            *(float4*)&wv[12] = *(const float4*)(wp + 12);
            const float* us = &up_s[kc + skh];
            short8 o0, o1;
#pragma unroll
            for (int i = 0; i < 8; i++) o0[i] = f2bf(wv[i] * us[i]);
#pragma unroll
            for (int i = 0; i < 8; i++) o1[i] = f2bf(wv[8 + i] * us[8 + i]);
            *(short8*)&Ws[sn * 40 + skh]     = o0;
            *(short8*)&Ws[sn * 40 + skh + 8] = o1;
        }
        __syncthreads();

        short8 a[4], bfr[4];
#pragma unroll
        for (int t = 0; t < 4; t++)
            a[t] = *(const short8*)&vp_s[(wn + t * 16 + l15) * 40 + quad * 8];
#pragma unroll
        for (int t = 0; t < 4; t++)
            bfr[t] = *(const short8*)&Ws[(wf + t * 16 + l15) * 40 + quad * 8];
#pragma unroll
        for (int tn = 0; tn < 4; tn++)
#pragma unroll
            for (int tf = 0; tf < 4; tf++)
                acc[tn][tf] = __builtin_amdgcn_mfma_f32_16x16x32_bf16(
                    a[tn], bfr[tf], acc[tn][tf], 0, 0, 0);
    }

    float bpv[4];
#pragma unroll
    for (int tf = 0; tf < 4; tf++) bpv[tf] = bp[f0 + wf + tf * 16 + l15];

    const size_t out_base = (size_t)bm * 128 * 256;
#pragma unroll
    for (int tn = 0; tn < 4; tn++) {
#pragma unroll
        for (int r = 0; r < 4; r++) {
            int n = wn + tn * 16 + quad * 4 + r;
            float* op = out + out_base + (size_t)n * 256 + f0 + wf + l15;
#pragma unroll
            for (int tf = 0; tf < 4; tf++) {
                float val = acc[tn][tf][r] + bpv[tf];
                op[tf * 16] = fmaxf(val, 0.0f);
            }
        }
    }
}

extern "C" void kernel_launch(void* const* d_in, const int* in_sizes, int n_in,
                              void* d_out, int out_size, void* d_ws, size_t ws_size,
                              hipStream_t stream) {
    const float* u  = (const float*)d_in[0];   // (32,32,1024)
    const float* v  = (const float*)d_in[1];   // (32,128,2048)
    const float* Wu = (const float*)d_in[2];   // (256,1024)
    const float* Wv = (const float*)d_in[3];   // (256,2048)
    const float* Wp = (const float*)d_in[4];   // (256,256)
    const float* bp = (const float*)d_in[5];   // (256,)
    float* out = (float*)d_out;                // (32,32,128,256)

    short* up_bf = (short*)d_ws;               // 1024*256 bf16 = 512 KB
    short* vp_bf = up_bf + 1024 * 256;         // 4096*256 bf16 = 2 MB

    // up = u @ Wu^T : rows=1024, D=1024 -> grid 16*4
    proj_kernel<<<dim3(16 * 4), dim3(256), 0, stream>>>(u, Wu, up_bf, 1024);
    // vp = v @ Wv^T : rows=4096, D=2048 -> grid 64*4
    proj_kernel<<<dim3(64 * 4), dim3(256), 0, stream>>>(v, Wv, vp_bf, 2048);
    // bilinear: 1024 (b,m) pairs x 2 f-halves
    bilinear_kernel<<<dim3(2048), dim3(256), 0, stream>>>(up_bf, vp_bf, Wp, bp, out);
}

// Round 2
// 220.391 us; speedup vs baseline: 1.2334x; 1.2334x over previous
//
#include <hip/hip_runtime.h>
#include <hip/hip_bf16.h>

// LowRankBilinearFusion on MI355X (gfx950)
// Pipeline (3 dispatches):
//  1. convert: u,v,Wu,Wv,Wp fp32 -> bf16 in d_ws (memory-bound, conversions free)
//  2. proj (merged): up_bf = u @ Wu^T (1024x256, D=1024)
//                    vp_bf = v @ Wv^T (4096x256, D=2048)   pure-bf16 MFMA GEMM
//  3. bilinear: per (b,m): o = relu( vp[b] @ (up[b,m] (.) Wp)^T + bp )
//     128x256x256 GEMM per (b,m); W' = up (.) Wp fused into LDS staging (bf16 in).

typedef __attribute__((ext_vector_type(8))) short short8;
typedef __attribute__((ext_vector_type(4))) float floatx4;

// Branch-free RNE fp32->bf16 (inputs are finite; no NaN path needed). ~3 VALU.
__device__ __forceinline__ short f2bf(float f) {
    union { float f; unsigned u; } cv; cv.f = f;
    unsigned r = cv.u + 0x7fffu + ((cv.u >> 16) & 1u);
    return (short)(r >> 16);
}
__device__ __forceinline__ float bf2f(short s) {
    union { unsigned u; float f; } cv;
    cv.u = ((unsigned)(unsigned short)s) << 16; return cv.f;
}

// ---------------------------------------------------------------------------
// Fused fp32 -> bf16 convert of all 5 inputs into one contiguous bf16 region.
// Segment order in dst: u | v | Wu | Wv | Wp. float4-in / short4-out.
// ---------------------------------------------------------------------------
#define N_U  1048576
#define N_V  8388608
#define N_WU 262144
#define N_WV 524288
#define N_WP 65536

__global__ __launch_bounds__(256) void convert_kernel(
    const float* __restrict__ u, const float* __restrict__ v,
    const float* __restrict__ Wu, const float* __restrict__ Wv,
    const float* __restrict__ Wp, short* __restrict__ dst)
{
    const int n_u = N_U / 4, n_v = N_V / 4, n_wu = N_WU / 4, n_wv = N_WV / 4,
              n_wp = N_WP / 4;
    const int total = n_u + n_v + n_wu + n_wv + n_wp;
    for (int i4 = blockIdx.x * blockDim.x + threadIdx.x; i4 < total;
         i4 += gridDim.x * blockDim.x) {
        const float* src; int off = i4;
        if (off < n_u) src = u;
        else { off -= n_u;
            if (off < n_v) src = v;
            else { off -= n_v;
                if (off < n_wu) src = Wu;
                else { off -= n_wu;
                    if (off < n_wv) src = Wv;
                    else { off -= n_wv; src = Wp; } } } }
        float4 f = *((const float4*)src + off);
        short4 o;
        o.x = f2bf(f.x); o.y = f2bf(f.y); o.z = f2bf(f.z); o.w = f2bf(f.w);
        *((short4*)dst + i4) = o;
    }
}

// ---------------------------------------------------------------------------
// Merged projection GEMM (pure bf16 in/out): C[row][c] = sum_d X[row][d]*W[c][d]
// Blocks 0..63: u-proj (rows=1024, D=1024); 64..319: v-proj (rows=4096, D=2048)
// 64x64 tile, 256 threads (2x2 waves of 32x32), K-chunks of 32.
// ---------------------------------------------------------------------------
__global__ __launch_bounds__(256) void proj_kernel(
    const short* __restrict__ Xu, const short* __restrict__ Wgu,
    short* __restrict__ Cu,
    const short* __restrict__ Xv, const short* __restrict__ Wgv,
    short* __restrict__ Cv)
{
    __shared__ short Xs[64 * 40];
    __shared__ short Wsh[64 * 40];

    const int tid  = threadIdx.x;
    const int lane = tid & 63;
    const int wave = tid >> 6;
    const int quad = lane >> 4;
    const int l15  = lane & 15;

    int blk = blockIdx.x;
    const short *X, *W; short* C; int D;
    if (blk < 64) { X = Xu; W = Wgu; C = Cu; D = 1024; }
    else          { blk -= 64; X = Xv; W = Wgv; C = Cv; D = 2048; }
    const int r0 = (blk >> 2) * 64;
    const int c0 = (blk & 3) * 64;
    const int wr = (wave >> 1) * 32;
    const int wc = (wave & 1) * 32;

    const int sr  = tid >> 2;        // 0..63
    const int skg = (tid & 3) * 8;   // 0,8,16,24

    floatx4 acc[2][2] = {};

    for (int kc = 0; kc < D; kc += 32) {
        __syncthreads();
        *(short8*)&Xs[sr * 40 + skg]  = *(const short8*)(X + (size_t)(r0 + sr) * D + kc + skg);
        *(short8*)&Wsh[sr * 40 + skg] = *(const short8*)(W + (size_t)(c0 + sr) * D + kc + skg);
        __syncthreads();

        short8 a[2], bfr[2];
#pragma unroll
        for (int t = 0; t < 2; t++)
            a[t] = *(const short8*)&Xs[(wr + t * 16 + l15) * 40 + quad * 8];
#pragma unroll
        for (int t = 0; t < 2; t++)
            bfr[t] = *(const short8*)&Wsh[(wc + t * 16 + l15) * 40 + quad * 8];
#pragma unroll
        for (int tn = 0; tn < 2; tn++)
#pragma unroll
            for (int tf = 0; tf < 2; tf++)
                acc[tn][tf] = __builtin_amdgcn_mfma_f32_16x16x32_bf16(
                    a[tn], bfr[tf], acc[tn][tf], 0, 0, 0);
    }

    // C/D layout: col=lane&15, row=quad*4+reg (verified m89/m91)
#pragma unroll
    for (int tn = 0; tn < 2; tn++)
#pragma unroll
        for (int tf = 0; tf < 2; tf++)
#pragma unroll
            for (int r = 0; r < 4; r++) {
                int row = r0 + wr + tn * 16 + quad * 4 + r;
                int col = c0 + wc + tf * 16 + l15;
                C[(size_t)row * 256 + col] = f2bf(acc[tn][tf][r]);
            }
}

// ---------------------------------------------------------------------------
// Bilinear fusion. One block = one (b,m) x one 128-wide f-half.
// n=128 x f=128 tile, 4 waves 2x2, each wave 64x64 (4x4 MFMA tiles).
// K=256 in chunks of 32; W'[f][k] = up[k]*Wp_bf[f][k] fused into staging.
// ---------------------------------------------------------------------------
__global__ __launch_bounds__(256) void bilinear_kernel(
    const short* __restrict__ up, const short* __restrict__ vp,
    const short* __restrict__ Wp, const float* __restrict__ bp,
    float* __restrict__ out)
{
    __shared__ short vp_s[128 * 40];
    __shared__ short Ws[128 * 40];
    __shared__ float up_s[256];

    const int tid  = threadIdx.x;
    const int lane = tid & 63;
    const int wave = tid >> 6;
    const int quad = lane >> 4;
    const int l15  = lane & 15;

    const int f_blk = blockIdx.x & 1;
    const int bm    = blockIdx.x >> 1;   // b*32 + m
    const int b     = bm >> 5;
    const int f0    = f_blk * 128;
    const int wn    = (wave >> 1) * 64;
    const int wf    = (wave & 1) * 64;

    up_s[tid] = bf2f(up[(size_t)bm * 256 + tid]);

    const int sn  = tid >> 1;          // 0..127 staging row
    const int skh = (tid & 1) * 16;    // 0 or 16

    floatx4 acc[4][4] = {};

    for (int kc = 0; kc < 256; kc += 32) {
        __syncthreads();   // also publishes up_s on first iteration
        {   // vp slice: 128 x 32 bf16 plain copy
            const short* p = vp + (size_t)(b * 128 + sn) * 256 + kc + skh;
            short8 v0 = *(const short8*)p;
            short8 v1 = *(const short8*)(p + 8);
            *(short8*)&vp_s[sn * 40 + skh]     = v0;
            *(short8*)&vp_s[sn * 40 + skh + 8] = v1;
        }
        {   // W' slice: 128 x 32 = bf16(Wp) * up_s[k]
            const short* wpp = Wp + (size_t)(f0 + sn) * 256 + kc + skh;
            short8 w0 = *(const short8*)wpp;
            short8 w1 = *(const short8*)(wpp + 8);
            float us[16];
            const float4* us4 = (const float4*)&up_s[kc + skh];
            *(float4*)&us[0]  = us4[0];
            *(float4*)&us[4]  = us4[1];
            *(float4*)&us[8]  = us4[2];
            *(float4*)&us[12] = us4[3];
            short8 o0, o1;
#pragma unroll
            for (int i = 0; i < 8; i++) o0[i] = f2bf(bf2f(w0[i]) * us[i]);
#pragma unroll
            for (int i = 0; i < 8; i++) o1[i] = f2bf(bf2f(w1[i]) * us[8 + i]);
            *(short8*)&Ws[sn * 40 + skh]     = o0;
            *(short8*)&Ws[sn * 40 + skh + 8] = o1;
        }
        __syncthreads();

        short8 a[4], bfr[4];
#pragma unroll
        for (int t = 0; t < 4; t++)
            a[t] = *(const short8*)&vp_s[(wn + t * 16 + l15) * 40 + quad * 8];
#pragma unroll
        for (int t = 0; t < 4; t++)
            bfr[t] = *(const short8*)&Ws[(wf + t * 16 + l15) * 40 + quad * 8];
#pragma unroll
        for (int tn = 0; tn < 4; tn++)
#pragma unroll
            for (int tf = 0; tf < 4; tf++)
                acc[tn][tf] = __builtin_amdgcn_mfma_f32_16x16x32_bf16(
                    a[tn], bfr[tf], acc[tn][tf], 0, 0, 0);
    }

    float bpv[4];
#pragma unroll
    for (int tf = 0; tf < 4; tf++) bpv[tf] = bp[f0 + wf + tf * 16 + l15];

    const size_t out_base = (size_t)bm * 128 * 256;
#pragma unroll
    for (int tn = 0; tn < 4; tn++)
#pragma unroll
        for (int r = 0; r < 4; r++) {
            int n = wn + tn * 16 + quad * 4 + r;
            float* op = out + out_base + (size_t)n * 256 + f0 + wf + l15;
#pragma unroll
            for (int tf = 0; tf < 4; tf++) {
                float val = acc[tn][tf][r] + bpv[tf];
                op[tf * 16] = fmaxf(val, 0.0f);
            }
        }
}

extern "C" void kernel_launch(void* const* d_in, const int* in_sizes, int n_in,
                              void* d_out, int out_size, void* d_ws, size_t ws_size,
                              hipStream_t stream) {
    const float* u  = (const float*)d_in[0];   // (32,32,1024)
    const float* v  = (const float*)d_in[1];   // (32,128,2048)
    const float* Wu = (const float*)d_in[2];   // (256,1024)
    const float* Wv = (const float*)d_in[3];   // (256,2048)
    const float* Wp = (const float*)d_in[4];   // (256,256)
    const float* bp = (const float*)d_in[5];   // (256,)
    float* out = (float*)d_out;                // (32,32,128,256)

    short* bf    = (short*)d_ws;
    short* u_bf  = bf;                 // 1,048,576
    short* v_bf  = u_bf + N_U;         // 8,388,608
    short* Wu_bf = v_bf + N_V;         // 262,144
    short* Wv_bf = Wu_bf + N_WU;       // 524,288
    short* Wp_bf = Wv_bf + N_WV;       // 65,536
    short* up_bf = Wp_bf + N_WP;       // 1024x256
    short* vp_bf = up_bf + 262144;     // 4096x256

    convert_kernel<<<dim3(2048), dim3(256), 0, stream>>>(u, v, Wu, Wv, Wp, bf);
    // blocks 0..63: up (16 rblk x 4 cblk); 64..319: vp (64 rblk x 4 cblk)
    proj_kernel<<<dim3(320), dim3(256), 0, stream>>>(
        u_bf, Wu_bf, up_bf, v_bf, Wv_bf, vp_bf);
    bilinear_kernel<<<dim3(2048), dim3(256), 0, stream>>>(
        up_bf, vp_bf, Wp_bf, bp, out);
}

// Round 3
// 214.312 us; speedup vs baseline: 1.2684x; 1.0284x over previous
//
#include <hip/hip_runtime.h>
#include <hip/hip_bf16.h>

// LowRankBilinearFusion on MI355X (gfx950)
// Pipeline (3 dispatches):
//  1. convert: u,v,Wu,Wv,Wp fp32 -> bf16 into d_ws (memory-bound, RNE free)
//  2. proj (merged): up_bf = u @ Wu^T (1024x256, D=1024)
//                    vp_bf = v @ Wv^T (4096x256, D=2048)
//     bf16 MFMA GEMM, staging via global_load_lds width=16 (m97 pattern)
//  3. bilinear: per (b,m): o = relu( vp[b] @ (up[b,m] (.) Wp)^T + bp )
//     128x256x256 GEMM per (b,m); W' = up (.) Wp fused into LDS staging with
//     trunc+v_perm packing; vp staged via global_load_lds.

typedef __attribute__((ext_vector_type(8))) short short8;
typedef __attribute__((ext_vector_type(4))) float floatx4;
typedef __attribute__((ext_vector_type(4))) unsigned uintx4;

// Branch-free RNE fp32->bf16 (finite inputs). Used where accuracy matters.
__device__ __forceinline__ short f2bf(float f) {
    union { float f; unsigned u; } cv; cv.f = f;
    unsigned r = cv.u + 0x7fffu + ((cv.u >> 16) & 1u);
    return (short)(r >> 16);
}
__device__ __forceinline__ float bf2f(short s) {
    union { unsigned u; float f; } cv;
    cv.u = ((unsigned)(unsigned short)s) << 16; return cv.f;
}
// Scale two bf16 by two fp32, pack truncated-bf16 pair into one dword.
// 5 VALU ops / 2 elems (2 lshl + 2 mul + 1 v_perm).
__device__ __forceinline__ unsigned scale2(short a, short b, float ua, float ub) {
    float x = __uint_as_float(((unsigned)(unsigned short)a) << 16) * ua;
    float y = __uint_as_float(((unsigned)(unsigned short)b) << 16) * ub;
    // dst = (hi16(y) << 16) | hi16(x)
    return __builtin_amdgcn_perm(__float_as_uint(y), __float_as_uint(x), 0x07060302);
}

#define GL2LDS(gptr, lptr) __builtin_amdgcn_global_load_lds(                    \
    (const __attribute__((address_space(1))) void*)(gptr),                      \
    (__attribute__((address_space(3))) void*)(lptr), 16, 0, 0)

// ---------------------------------------------------------------------------
#define N_U  1048576
#define N_V  8388608
#define N_WU 262144
#define N_WV 524288
#define N_WP 65536

__global__ __launch_bounds__(256) void convert_kernel(
    const float* __restrict__ u, const float* __restrict__ v,
    const float* __restrict__ Wu, const float* __restrict__ Wv,
    const float* __restrict__ Wp, short* __restrict__ dst)
{
    const int n_u = N_U / 4, n_v = N_V / 4, n_wu = N_WU / 4, n_wv = N_WV / 4,
              n_wp = N_WP / 4;
    const int total = n_u + n_v + n_wu + n_wv + n_wp;
    for (int i4 = blockIdx.x * blockDim.x + threadIdx.x; i4 < total;
         i4 += gridDim.x * blockDim.x) {
        const float* src; int off = i4;
        if (off < n_u) src = u;
        else { off -= n_u;
            if (off < n_v) src = v;
            else { off -= n_v;
                if (off < n_wu) src = Wu;
                else { off -= n_wu;
                    if (off < n_wv) src = Wv;
                    else { off -= n_wv; src = Wp; } } } }
        float4 f = *((const float4*)src + off);
        short4 o;
        o.x = f2bf(f.x); o.y = f2bf(f.y); o.z = f2bf(f.z); o.w = f2bf(f.w);
        *((short4*)dst + i4) = o;
    }
}

// ---------------------------------------------------------------------------
// Merged projection GEMM (bf16 in/out): C[row][c] = sum_d X[row][d]*W[c][d]
// Blocks 0..63: u-proj (rows=1024, D=1024); 64..319: v-proj (rows=4096, D=2048)
// 64x64 tile, 256 threads (2x2 waves of 32x32), K-chunks of 32.
// Staging: global_load_lds width=16, unpadded 64 B rows (LDS dst = tid*16).
// ---------------------------------------------------------------------------
__global__ __launch_bounds__(256) void proj_kernel(
    const short* __restrict__ Xu, const short* __restrict__ Wgu,
    short* __restrict__ Cu,
    const short* __restrict__ Xv, const short* __restrict__ Wgv,
    short* __restrict__ Cv)
{
    __shared__ short Xs[64 * 32];    // unpadded: required by global_load_lds
    __shared__ short Wsh[64 * 32];

    const int tid  = threadIdx.x;
    const int lane = tid & 63;
    const int wave = tid >> 6;
    const int quad = lane >> 4;
    const int l15  = lane & 15;

    int blk = blockIdx.x;
    const short *X, *W; short* C; int D;
    if (blk < 64) { X = Xu; W = Wgu; C = Cu; D = 1024; }
    else          { blk -= 64; X = Xv; W = Wgv; C = Cv; D = 2048; }
    const int r0 = (blk >> 2) * 64;
    const int c0 = (blk & 3) * 64;
    const int wr = (wave >> 1) * 32;
    const int wc = (wave & 1) * 32;

    const int sr  = tid >> 2;        // 0..63 staging row
    const int skg = (tid & 3) * 8;   // 0,8,16,24 (shorts)
    // LDS offset sr*32+skg shorts == tid*16 bytes: matches base + lane*16.

    floatx4 acc[2][2] = {};

    for (int kc = 0; kc < D; kc += 32) {
        __syncthreads();
        GL2LDS(X + (size_t)(r0 + sr) * D + kc + skg, &Xs[sr * 32 + skg]);
        GL2LDS(W + (size_t)(c0 + sr) * D + kc + skg, &Wsh[sr * 32 + skg]);
        __syncthreads();   // drains vmcnt -> LDS visible

        short8 a[2], bfr[2];
#pragma unroll
        for (int t = 0; t < 2; t++)
            a[t] = *(const short8*)&Xs[(wr + t * 16 + l15) * 32 + quad * 8];
#pragma unroll
        for (int t = 0; t < 2; t++)
            bfr[t] = *(const short8*)&Wsh[(wc + t * 16 + l15) * 32 + quad * 8];
#pragma unroll
        for (int tn = 0; tn < 2; tn++)
#pragma unroll
            for (int tf = 0; tf < 2; tf++)
                acc[tn][tf] = __builtin_amdgcn_mfma_f32_16x16x32_bf16(
                    a[tn], bfr[tf], acc[tn][tf], 0, 0, 0);
    }

    // C/D layout: col=lane&15, row=quad*4+reg (verified m89/m91)
#pragma unroll
    for (int tn = 0; tn < 2; tn++)
#pragma unroll
        for (int tf = 0; tf < 2; tf++)
#pragma unroll
            for (int r = 0; r < 4; r++) {
                int row = r0 + wr + tn * 16 + quad * 4 + r;
                int col = c0 + wc + tf * 16 + l15;
                C[(size_t)row * 256 + col] = f2bf(acc[tn][tf][r]);
            }
}

// ---------------------------------------------------------------------------
// Bilinear fusion. One block = one (b,m) x one 128-wide f-half.
// n=128 x f=128 tile, 4 waves 2x2, each wave 64x64 (4x4 MFMA tiles).
// K=256 in chunks of 32. vp staged via global_load_lds; W' = up(.)Wp staged
// with trunc+perm packing (2.5 VALU/elem).
// ---------------------------------------------------------------------------
__global__ __launch_bounds__(256) void bilinear_kernel(
    const short* __restrict__ up, const short* __restrict__ vp,
    const short* __restrict__ Wp, const float* __restrict__ bp,
    float* __restrict__ out)
{
    __shared__ short vp_s[128 * 32];   // unpadded (global_load_lds)
    __shared__ short Ws[128 * 32];     // unpadded (symmetric reads)
    __shared__ float up_s[256];

    const int tid  = threadIdx.x;
    const int lane = tid & 63;
    const int wave = tid >> 6;
    const int quad = lane >> 4;
    const int l15  = lane & 15;

    const int f_blk = blockIdx.x & 1;
    const int bm    = blockIdx.x >> 1;   // b*32 + m
    const int b     = bm >> 5;
    const int f0    = f_blk * 128;
    const int wn    = (wave >> 1) * 64;
    const int wf    = (wave & 1) * 64;

    up_s[tid] = bf2f(up[(size_t)bm * 256 + tid]);

    // vp staging: two 16B issues/thread; issue i covers rows 64*i..64*i+63
    const int sr  = tid >> 2;          // 0..63
    const int skg = (tid & 3) * 8;     // 0,8,16,24 (shorts)
    // W' staging: 16 elems/thread
    const int sn  = tid >> 1;          // 0..127
    const int skh = (tid & 1) * 16;    // 0 or 16

    floatx4 acc[4][4] = {};

    for (int kc = 0; kc < 256; kc += 32) {
        __syncthreads();   // also publishes up_s on first iteration
        {   // vp slice 128x32 via async global->LDS (8 KB)
            const short* g = vp + (size_t)(b * 128 + sr) * 256 + kc + skg;
            GL2LDS(g,                 &vp_s[sr * 32 + skg]);
            GL2LDS(g + 64 * 256,      &vp_s[(64 + sr) * 32 + skg]);
        }
        {   // W' slice: 128x32 = trunc_bf16( bf2f(Wp) * up[k] )
            const short* wpp = Wp + (size_t)(f0 + sn) * 256 + kc + skh;
            short8 w0 = *(const short8*)wpp;
            short8 w1 = *(const short8*)(wpp + 8);
            const float* us = &up_s[kc + skh];
            float uv[16];
            *(float4*)&uv[0]  = *(const float4*)(us);
            *(float4*)&uv[4]  = *(const float4*)(us + 4);
            *(float4*)&uv[8]  = *(const float4*)(us + 8);
            *(float4*)&uv[12] = *(const float4*)(us + 12);
            uintx4 o0, o1;
#pragma unroll
            for (int i = 0; i < 4; i++)
                o0[i] = scale2(w0[2 * i], w0[2 * i + 1], uv[2 * i], uv[2 * i + 1]);
#pragma unroll
            for (int i = 0; i < 4; i++)
                o1[i] = scale2(w1[2 * i], w1[2 * i + 1], uv[8 + 2 * i], uv[9 + 2 * i]);
            *(uintx4*)&Ws[sn * 32 + skh]     = o0;
            *(uintx4*)&Ws[sn * 32 + skh + 8] = o1;
        }
        __syncthreads();

        short8 a[4], bfr[4];
#pragma unroll
        for (int t = 0; t < 4; t++)
            a[t] = *(const short8*)&vp_s[(wn + t * 16 + l15) * 32 + quad * 8];
#pragma unroll
        for (int t = 0; t < 4; t++)
            bfr[t] = *(const short8*)&Ws[(wf + t * 16 + l15) * 32 + quad * 8];
#pragma unroll
        for (int tn = 0; tn < 4; tn++)
#pragma unroll
            for (int tf = 0; tf < 4; tf++)
                acc[tn][tf] = __builtin_amdgcn_mfma_f32_16x16x32_bf16(
                    a[tn], bfr[tf], acc[tn][tf], 0, 0, 0);
    }

    float bpv[4];
#pragma unroll
    for (int tf = 0; tf < 4; tf++) bpv[tf] = bp[f0 + wf + tf * 16 + l15];

    const size_t out_base = (size_t)bm * 128 * 256;
#pragma unroll
    for (int tn = 0; tn < 4; tn++)
#pragma unroll
        for (int r = 0; r < 4; r++) {
            int n = wn + tn * 16 + quad * 4 + r;
            float* op = out + out_base + (size_t)n * 256 + f0 + wf + l15;
#pragma unroll
            for (int tf = 0; tf < 4; tf++) {
                float val = acc[tn][tf][r] + bpv[tf];
                op[tf * 16] = fmaxf(val, 0.0f);
            }
        }
}

extern "C" void kernel_launch(void* const* d_in, const int* in_sizes, int n_in,
                              void* d_out, int out_size, void* d_ws, size_t ws_size,
                              hipStream_t stream) {
    const float* u  = (const float*)d_in[0];   // (32,32,1024)
    const float* v  = (const float*)d_in[1];   // (32,128,2048)
    const float* Wu = (const float*)d_in[2];   // (256,1024)
    const float* Wv = (const float*)d_in[3];   // (256,2048)
    const float* Wp = (const float*)d_in[4];   // (256,256)
    const float* bp = (const float*)d_in[5];   // (256,)
    float* out = (float*)d_out;                // (32,32,128,256)

    short* bf    = (short*)d_ws;
    short* u_bf  = bf;                 // 1,048,576
    short* v_bf  = u_bf + N_U;         // 8,388,608
    short* Wu_bf = v_bf + N_V;         // 262,144
    short* Wv_bf = Wu_bf + N_WU;       // 524,288
    short* Wp_bf = Wv_bf + N_WV;       // 65,536
    short* up_bf = Wp_bf + N_WP;       // 1024x256
    short* vp_bf = up_bf + 262144;     // 4096x256

    convert_kernel<<<dim3(2048), dim3(256), 0, stream>>>(u, v, Wu, Wv, Wp, bf);
    // blocks 0..63: up (16 rblk x 4 cblk); 64..319: vp (64 rblk x 4 cblk)
    proj_kernel<<<dim3(320), dim3(256), 0, stream>>>(
        u_bf, Wu_bf, up_bf, v_bf, Wv_bf, vp_bf);
    bilinear_kernel<<<dim3(2048), dim3(256), 0, stream>>>(
        up_bf, vp_bf, Wp_bf, bp, out);
}